// Round 14
// baseline (164.029 us; speedup 1.0000x reference)
//
#include <hip/hip_runtime.h>

typedef __bf16 bf16_t;
typedef __bf16 bf16x8 __attribute__((ext_vector_type(8)));
typedef __bf16 bf16x4 __attribute__((ext_vector_type(4)));
typedef float f32x4 __attribute__((ext_vector_type(4)));

#define M_DIM 4096
#define OUTF 2048
#define INF 2048
#define LDK 4096
#define NT 64
// 3M geometry
#define LDK2 2048
#define NT3 96        // 3 phases x 32 K-tiles (BK=64, K=2048)

__device__ __forceinline__ float mfq(float x) { return x; }

// ---------------------------------------------------------------------------
// Pack for 3M: S=xr+xi, XI, XR (each 4096x2048 bf16) and
//              B1=wr, B2=-(wr+wi), B3=wi-wr (each 2048x2048 bf16)
// ws elems: S@0, XI@8388608, XR@16777216, B1@25165824, B2@29360128,
//           B3@33554432, total 37748736 elems = 72 MiB.
// ---------------------------------------------------------------------------
__global__ __launch_bounds__(256) void pack_3m(
    const float* __restrict__ xre, const float* __restrict__ xim,
    const float* __restrict__ wre, const float* __restrict__ wim,
    bf16_t* __restrict__ ws)
{
  size_t e = ((size_t)blockIdx.x * 256 + threadIdx.x) * 8;
  const size_t AB = 25165824;   // 3 * 4096*2048
  bf16x8 v;
  if (e < AB) {
    int seg = (int)(e / 8388608);
    size_t off = e - (size_t)seg * 8388608;
    size_t base = (off >> 11) * (size_t)INF + (off & 2047);
    const float4* pr = reinterpret_cast<const float4*>(xre + base);
    const float4* pi = reinterpret_cast<const float4*>(xim + base);
#pragma unroll
    for (int h = 0; h < 2; ++h) {
      float4 fr = pr[h], fi = pi[h];
      float r[4] = {fr.x, fr.y, fr.z, fr.w};
      float ii[4] = {fi.x, fi.y, fi.z, fi.w};
#pragma unroll
      for (int j = 0; j < 4; ++j) {
        float o = (seg == 0) ? (r[j] + ii[j]) : ((seg == 1) ? ii[j] : r[j]);
        v[h * 4 + j] = (bf16_t)o;
      }
    }
  } else {
    size_t eb = e - AB;
    int seg = (int)(eb / 4194304);
    size_t off = eb - (size_t)seg * 4194304;
    size_t base = (off >> 11) * (size_t)INF + (off & 2047);
    const float4* pr = reinterpret_cast<const float4*>(wre + base);
    const float4* pi = reinterpret_cast<const float4*>(wim + base);
#pragma unroll
    for (int h = 0; h < 2; ++h) {
      float4 fr = pr[h], fi = pi[h];
      float r[4] = {fr.x, fr.y, fr.z, fr.w};
      float ii[4] = {fi.x, fi.y, fi.z, fi.w};
#pragma unroll
      for (int j = 0; j < 4; ++j) {
        float o = (seg == 0) ? r[j] : ((seg == 1) ? -(r[j] + ii[j]) : (ii[j] - r[j]));
        v[h * 4 + j] = (bf16_t)o;
      }
    }
  }
  *reinterpret_cast<bf16x8*>(ws + e) = v;
}

// ---------------------------------------------------------------------------
__device__ __forceinline__ void gld_lds16(const void* g, void* l) {
  __builtin_amdgcn_global_load_lds(
      (const __attribute__((address_space(1))) void*)g,
      (__attribute__((address_space(3))) void*)l,
      16, 0, 0);
}

// ---------------------------------------------------------------------------
// 3M GEMM (R14): block = 256(M) x 128(N) of BOTH out_re and out_im.
//   3 phases (m1/m2/m3), 32 K-tiles each (BK=64, K=2048). Phase1 -> accR,
//   copy accR->accI, phase2 -> accR (B2 pre-negated => accR=out_re),
//   phase3 -> accI (=out_im). 8 waves 4Mx2N: wave 64x64, 4x4 frags/acc.
//   R3-proven 4-phase K-tile skeleton; swizzle (verified conflicts==0):
//     phys_kbyte = logical_kbyte ^ ((row&3)<<4) ^ (((row>>2)&1)<<6)
//   Stage cadence: P1:(u+1).Ah1, P2:(u+1).B, P4:(u+2).Ah0 + vmcnt(2).
// ---------------------------------------------------------------------------
__global__ __launch_bounds__(512, 2) void gemm3m(
    const bf16_t* __restrict__ ws, float* __restrict__ out)
{
  // LDS: buf c at c*49152: A 256x64 (32 KB, row stride 128B) | B 128x64 (16 KB)
  __shared__ alignas(16) bf16_t lds[2 * 24576];
  char* Lb = (char*)lds;

  const int tid  = threadIdx.x;
  const int lane = tid & 63;
  const int wid  = tid >> 6;
  const int wm2  = wid >> 1;    // 0..3 -> rows wm2*64
  const int wn2  = wid & 1;     // 0..1 -> cols wn2*64
  const int lr   = lane & 15;
  const int kg   = (lane >> 4) * 16;
  const int xm   = ((lr & 3) << 4) | (((lr >> 2) & 1) << 6);

  int bid = blockIdx.x;
  int swz = (bid & 7) * 32 + (bid >> 3);
  const int bm = swz >> 4;   // 0..15 (256 rows)
  const int bn = swz & 15;   // 0..15 (128 cols)

  // staging source constants: call j writes LDS bytes j*8192 + tid*16
  const int rowbase = tid >> 3;           // 0..63
  const int pby     = (tid & 7) * 16;     // byte in 128B row
  const int Lg      = pby ^ ((rowbase & 3) << 4) ^ (((rowbase >> 2) & 1) << 6);
  const int kelem   = Lg >> 1;            // 0..63
  const int dst16   = tid * 16;

  const bf16_t* Sb  = ws;
  const bf16_t* XIb = ws + 8388608;
  const bf16_t* XRb = ws + 16777216;
  const bf16_t* B1b = ws + 25165824;
  const bf16_t* B2b = ws + 29360128;
  const bf16_t* B3b = ws + 33554432;

  // per-thread A/B source bases (add (h*128+j*64)*LDK2 + lt*64 per call)
  const size_t aoff = (size_t)(bm * 256 + rowbase) * LDK2 + kelem;
  const size_t boff = (size_t)(bn * 128 + rowbase) * LDK2 + kelem;
  const bf16_t* aB[3] = {Sb + aoff, XIb + aoff, XRb + aoff};
  const bf16_t* bB[3] = {B1b + boff, B2b + boff, B3b + boff};

#define STAGE_AH(u, h, c) do {                                                 \
    int p_ = (u) >> 5, lt_ = (u) & 31;                                         \
    const bf16_t* ab_ = aB[0];                                                 \
    if (p_ == 1) ab_ = aB[1]; else if (p_ == 2) ab_ = aB[2];                   \
    _Pragma("unroll")                                                          \
    for (int j_ = 0; j_ < 2; ++j_)                                             \
      gld_lds16(ab_ + (size_t)((h) * 128 + j_ * 64) * LDK2 + lt_ * 64,         \
                Lb + (c) * 49152 + (h) * 16384 + j_ * 8192 + dst16);           \
  } while (0)
#define STAGE_B3(u, c) do {                                                    \
    int p_ = (u) >> 5, lt_ = (u) & 31;                                         \
    const bf16_t* bb_ = bB[0];                                                 \
    if (p_ == 1) bb_ = bB[1]; else if (p_ == 2) bb_ = bB[2];                   \
    _Pragma("unroll")                                                          \
    for (int j_ = 0; j_ < 2; ++j_)                                             \
      gld_lds16(bb_ + (size_t)(j_ * 64) * LDK2 + lt_ * 64,                     \
                Lb + (c) * 49152 + 32768 + j_ * 8192 + dst16);                 \
  } while (0)
#define RD_A3(c, h, m_, ks)                                                    \
  (*(const bf16x8*)(Lb + (c) * 49152 +                                         \
      (wm2 * 64 + (h) * 32 + (m_) * 16 + lr) * 128 + ((((ks) * 64) | kg) ^ xm)))
#define RD_B3(c, g, n_, ks)                                                    \
  (*(const bf16x8*)(Lb + (c) * 49152 + 32768 +                                 \
      (wn2 * 64 + (g) * 32 + (n_) * 16 + lr) * 128 + ((((ks) * 64) | kg) ^ xm)))
#define BAR()   __builtin_amdgcn_s_barrier()
#define LGKM0() asm volatile("s_waitcnt lgkmcnt(0)" ::: "memory")
#define MQ(ACC, h, g, AF, BF) do {                                             \
    __builtin_amdgcn_s_setprio(1);                                             \
    _Pragma("unroll")                                                          \
    for (int m_ = 0; m_ < 2; ++m_)                                             \
    _Pragma("unroll")                                                          \
    for (int n_ = 0; n_ < 2; ++n_) {                                           \
      f32x4 v_ = ACC[(h) * 2 + m_][(g) * 2 + n_];                              \
      v_ = __builtin_amdgcn_mfma_f32_16x16x32_bf16(AF[m_][0], BF[n_][0], v_,   \
                                                   0, 0, 0);                   \
      v_ = __builtin_amdgcn_mfma_f32_16x16x32_bf16(AF[m_][1], BF[n_][1], v_,   \
                                                   0, 0, 0);                   \
      ACC[(h) * 2 + m_][(g) * 2 + n_] = v_;                                    \
    }                                                                          \
    __builtin_amdgcn_s_setprio(0);                                             \
  } while (0)
#define KTILE(u, ACC) do {                                                     \
    const int c_ = (u) & 1;                                                    \
    bf16x8 a0[2][2], a1[2][2], b0[2][2], b1[2][2];                             \
    _Pragma("unroll")                                                          \
    for (int m_ = 0; m_ < 2; ++m_) {                                           \
      a0[m_][0] = RD_A3(c_, 0, m_, 0); a0[m_][1] = RD_A3(c_, 0, m_, 1);        \
    }                                                                          \
    _Pragma("unroll")                                                          \
    for (int n_ = 0; n_ < 2; ++n_) {                                           \
      b0[n_][0] = RD_B3(c_, 0, n_, 0); b0[n_][1] = RD_B3(c_, 0, n_, 1);        \
    }                                                                          \
    if ((u) + 1 < NT3) STAGE_AH((u) + 1, 1, c_ ^ 1);                           \
    BAR(); LGKM0();                                                            \
    MQ(ACC, 0, 0, a0, b0);                                                     \
    BAR();                                                                     \
    _Pragma("unroll")                                                          \
    for (int n_ = 0; n_ < 2; ++n_) {                                           \
      b1[n_][0] = RD_B3(c_, 1, n_, 0); b1[n_][1] = RD_B3(c_, 1, n_, 1);        \
    }                                                                          \
    if ((u) + 1 < NT3) STAGE_B3((u) + 1, c_ ^ 1);                              \
    BAR(); LGKM0();                                                            \
    MQ(ACC, 0, 1, a0, b1);                                                     \
    BAR();                                                                     \
    _Pragma("unroll")                                                          \
    for (int m_ = 0; m_ < 2; ++m_) {                                           \
      a1[m_][0] = RD_A3(c_, 1, m_, 0); a1[m_][1] = RD_A3(c_, 1, m_, 1);        \
    }                                                                          \
    BAR(); LGKM0();                                                            \
    MQ(ACC, 1, 1, a1, b1);                                                     \
    BAR();                                                                     \
    if ((u) + 2 < NT3) STAGE_AH((u) + 2, 0, c_);                               \
    MQ(ACC, 1, 0, a1, b0);                                                     \
    if ((u) + 2 < NT3) {                                                       \
      asm volatile("s_waitcnt vmcnt(2)" ::: "memory");                         \
    } else if ((u) + 1 < NT3) {                                                \
      asm volatile("s_waitcnt vmcnt(0)" ::: "memory");                         \
    }                                                                          \
    BAR();                                                                     \
  } while (0)

  f32x4 accR[4][4], accI[4][4];
#pragma unroll
  for (int i = 0; i < 4; ++i)
#pragma unroll
    for (int j = 0; j < 4; ++j)
      accR[i][j] = (f32x4){0.f, 0.f, 0.f, 0.f};

  // Prologue: tile0 A(4)+B(2) -> buf0; tile1.Ah0 (2) -> buf1; vmcnt(2).
  STAGE_AH(0, 0, 0); STAGE_AH(0, 1, 0);
  STAGE_B3(0, 0);
  STAGE_AH(1, 0, 1);
  asm volatile("s_waitcnt vmcnt(2)" ::: "memory");
  BAR();

  for (int t = 0; t < 32; ++t) KTILE(t, accR);          // phase 1: m1

#pragma unroll
  for (int i = 0; i < 4; ++i)
#pragma unroll
    for (int j = 0; j < 4; ++j)
      accI[i][j] = accR[i][j];                          // accI = m1

  for (int t = 32; t < 64; ++t) KTILE(t, accR);         // accR = m1 - m2 = re
  for (int t = 64; t < 96; ++t) KTILE(t, accI);         // accI = m1 + m3 = im

  // Epilogue: C/D layout col=lane&15, row=(lane>>4)*4+j (verified m89/m91)
  const size_t imOff = (size_t)M_DIM * OUTF;
  const int fq = (lane >> 4) * 4;
#pragma unroll
  for (int Mt = 0; Mt < 4; ++Mt) {
    int gr = bm * 256 + wm2 * 64 + Mt * 16 + fq;
#pragma unroll
    for (int Nt = 0; Nt < 4; ++Nt) {
      int gc = bn * 128 + wn2 * 64 + Nt * 16 + lr;
#pragma unroll
      for (int j = 0; j < 4; ++j) {
        out[(size_t)(gr + j) * OUTF + gc]         = accR[Mt][Nt][j];
        out[imOff + (size_t)(gr + j) * OUTF + gc] = accI[Mt][Nt][j];
      }
    }
  }
#undef STAGE_AH
#undef STAGE_B3
#undef RD_A3
#undef RD_B3
#undef BAR
#undef LGKM0
#undef MQ
#undef KTILE
}

// ===========================================================================
// Fallback chain (ws in [64,72) MiB): R8 pack + gemm256 (best classic, 117us)
// ===========================================================================
__global__ __launch_bounds__(256) void pack_ab(
    const float* __restrict__ xre, const float* __restrict__ xim,
    const float* __restrict__ wre, const float* __restrict__ wim,
    bf16_t* __restrict__ Abf, bf16_t* __restrict__ Bbf)
{
  size_t gid = (size_t)blockIdx.x * 256 + threadIdx.x;
  size_t e8  = gid * 8;
  const size_t MAT = (size_t)4096 * 4096;
  bool isB = e8 >= MAT;
  size_t e = isB ? (e8 - MAT) : e8;
  int row = (int)(e >> 12);
  int k   = (int)(e & 4095);
  const float* src;
  float s = 1.0f;
  if (!isB) {
    src = (k < INF) ? (xre + (size_t)row * INF + k)
                    : (xim + (size_t)row * INF + (k - INF));
  } else {
    if (row < OUTF) {
      if (k < INF) { src = wre + (size_t)row * INF + k; }
      else         { src = wim + (size_t)row * INF + (k - INF); s = -1.0f; }
    } else {
      int o = row - OUTF;
      src = (k < INF) ? (wim + (size_t)o * INF + k)
                      : (wre + (size_t)o * INF + (k - INF));
    }
  }
  const float4* p = reinterpret_cast<const float4*>(src);
  float4 f0 = p[0];
  float4 f1 = p[1];
  bf16x8 v;
  v[0] = (bf16_t)(f0.x * s); v[1] = (bf16_t)(f0.y * s);
  v[2] = (bf16_t)(f0.z * s); v[3] = (bf16_t)(f0.w * s);
  v[4] = (bf16_t)(f1.x * s); v[5] = (bf16_t)(f1.y * s);
  v[6] = (bf16_t)(f1.z * s); v[7] = (bf16_t)(f1.w * s);
  bf16_t* dst = (isB ? Bbf : Abf) + e;
  *reinterpret_cast<bf16x8*>(dst) = v;
}

template<int QM, int QN>
__device__ __forceinline__ void mfma_quad(f32x4 (&acc)[8][4],
                                          const bf16x8 (&aF)[4][2],
                                          const bf16x8 (&bF)[2][2]) {
  __builtin_amdgcn_s_setprio(1);
#pragma unroll
  for (int m = 0; m < 4; ++m)
#pragma unroll
    for (int n = 0; n < 2; ++n) {
      f32x4 v = acc[QM * 4 + m][QN * 2 + n];
      v = __builtin_amdgcn_mfma_f32_16x16x32_bf16(aF[m][0], bF[n][0], v, 0, 0, 0);
      v = __builtin_amdgcn_mfma_f32_16x16x32_bf16(aF[m][1], bF[n][1], v, 0, 0, 0);
      acc[QM * 4 + m][QN * 2 + n] = v;
    }
  __builtin_amdgcn_s_setprio(0);
}

__global__ __launch_bounds__(512, 2) void gemm256(
    const bf16_t* __restrict__ A, const bf16_t* __restrict__ B,
    float* __restrict__ out)
{
  __shared__ alignas(16) bf16_t lds[2 * 32768];
  char* Lb = (char*)lds;
  const int tid  = threadIdx.x;
  const int lane = tid & 63;
  const int wid  = tid >> 6;
  const int wm   = wid >> 2;
  const int wn   = wid & 3;
  const int lr   = lane & 15;
  const int kg   = (lane >> 4) * 16;
  const int xm   = ((lr & 3) << 4) | (((lr >> 2) & 1) << 6);
  int bid = blockIdx.x;
  int swz = (bid & 7) * 32 + (bid >> 3);
  const int bm = swz >> 4;
  const int bn = swz & 15;
  int rS[2], kS[2];
#pragma unroll
  for (int j = 0; j < 2; ++j) {
    int P   = j * 8192 + tid * 16;
    int row = P >> 7;
    int p   = P & 127;
    int L   = p ^ ((row & 3) << 4) ^ (((row >> 2) & 1) << 6);
    rS[j] = row;
    kS[j] = L >> 1;
  }
  const bf16_t* As0 = A + (size_t)(bm * 256 + rS[0]) * LDK + kS[0];
  const bf16_t* As1 = A + (size_t)(bm * 256 + rS[1]) * LDK + kS[1];
  const bf16_t* Bs0 = B + (size_t)(bn * 256 + rS[0]) * LDK + kS[0];
  const bf16_t* Bs1 = B + (size_t)(bn * 256 + rS[1]) * LDK + kS[1];
  const int dst16 = tid * 16;
#define STAGE_A(t, h, c) do {                                                  \
    gld_lds16(As0 + (size_t)(h) * 128 * LDK + (t) * 64,                        \
              Lb + (c) * 65536 + (h) * 16384 + dst16);                         \
    gld_lds16(As1 + (size_t)(h) * 128 * LDK + (t) * 64,                        \
              Lb + (c) * 65536 + (h) * 16384 + 8192 + dst16);                  \
  } while (0)
#define STAGE_B(t, h, c) do {                                                  \
    gld_lds16(Bs0 + (size_t)(h) * 128 * LDK + (t) * 64,                        \
              Lb + (c) * 65536 + 32768 + (h) * 16384 + dst16);                 \
    gld_lds16(Bs1 + (size_t)(h) * 128 * LDK + (t) * 64,                        \
              Lb + (c) * 65536 + 32768 + (h) * 16384 + 8192 + dst16);          \
  } while (0)
#define RD_A(c, qm, m, ks)                                                     \
  (*(const bf16x8*)(Lb + (c) * 65536 + wm * 16384 +                            \
                    ((qm) * 64 + (m) * 16 + lr) * 128 +                        \
                    ((((ks) * 64) | kg) ^ xm)))
#define RD_B(c, qn, n, ks)                                                     \
  (*(const bf16x8*)(Lb + (c) * 65536 + 32768 + (wn >> 1) * 16384 +             \
                    ((wn & 1) * 64 + (qn) * 32 + (n) * 16 + lr) * 128 +        \
                    ((((ks) * 64) | kg) ^ xm)))
#define BAR()   __builtin_amdgcn_s_barrier()
#define SB()    __builtin_amdgcn_sched_barrier(0)
#define ISSUE_Q1(c) do {                                                       \
    _Pragma("unroll")                                                          \
    for (int m_ = 0; m_ < 4; ++m_) {                                           \
      a0[m_][0] = RD_A(c, 0, m_, 0);                                           \
      a0[m_][1] = RD_A(c, 0, m_, 1);                                           \
    }                                                                          \
    _Pragma("unroll")                                                          \
    for (int n_ = 0; n_ < 2; ++n_) {                                           \
      b0[n_][0] = RD_B(c, 0, n_, 0);                                           \
      b0[n_][1] = RD_B(c, 0, n_, 1);                                           \
    }                                                                          \
  } while (0)
  f32x4 acc[8][4];
#pragma unroll
  for (int i = 0; i < 8; ++i)
#pragma unroll
    for (int j = 0; j < 4; ++j)
      acc[i][j] = (f32x4){0.f, 0.f, 0.f, 0.f};
  bf16x8 a0[4][2], b0[2][2];
  STAGE_A(0, 0, 0); STAGE_A(0, 1, 0);
  STAGE_B(0, 0, 0); STAGE_B(0, 1, 0);
  STAGE_A(1, 0, 1);
  asm volatile("s_waitcnt vmcnt(2)" ::: "memory");
  BAR();
  ISSUE_Q1(0);
  SB();
  for (int t = 0; t < NT; ++t) {
    const int c = t & 1;
    bf16x8 a1[4][2], b1[2][2];
    if (t + 1 < NT) STAGE_A(t + 1, 1, c ^ 1);
#pragma unroll
    for (int n = 0; n < 2; ++n) {
      b1[n][0] = RD_B(c, 1, n, 0);
      b1[n][1] = RD_B(c, 1, n, 1);
    }
    SB();
    asm volatile("s_waitcnt lgkmcnt(4)" ::: "memory");
    SB();
    mfma_quad<0, 0>(acc, a0, b0);
    if (t + 1 < NT) STAGE_B(t + 1, 0, c ^ 1);
#pragma unroll
    for (int m = 0; m < 4; ++m) {
      a1[m][0] = RD_A(c, 1, m, 0);
      a1[m][1] = RD_A(c, 1, m, 1);
    }
    SB();
    asm volatile("s_waitcnt lgkmcnt(8)" ::: "memory");
    SB();
    mfma_quad<0, 1>(acc, a0, b1);
    if (t + 1 < NT) STAGE_B(t + 1, 1, c ^ 1);
    asm volatile("s_waitcnt lgkmcnt(0)" ::: "memory");
    SB();
    mfma_quad<1, 1>(acc, a1, b1);
    BAR();
    if (t + 2 < NT) STAGE_A(t + 2, 0, c);
    if (t + 2 < NT) {
      asm volatile("s_waitcnt vmcnt(2)" ::: "memory");
    } else if (t + 1 < NT) {
      asm volatile("s_waitcnt vmcnt(0)" ::: "memory");
    }
    BAR();
    mfma_quad<1, 0>(acc, a1, b0);
    if (t + 1 < NT) {
      SB();
      ISSUE_Q1(c ^ 1);
      SB();
    }
  }
  const size_t imOff = (size_t)M_DIM * OUTF;
  const int fq = (lane >> 4) * 4;
  const bool isIm = (bn * 256) >= OUTF;
  float* obase = out + (isIm ? imOff : 0);
  const int colBase = bn * 256 - (isIm ? OUTF : 0) + wn * 64;
#pragma unroll
  for (int ar = 0; ar < 8; ++ar) {
    int gr = bm * 256 + wm * 128 + ar * 16 + fq;
#pragma unroll
    for (int cc = 0; cc < 4; ++cc) {
      int gc = colBase + cc * 16 + lr;
#pragma unroll
      for (int j = 0; j < 4; ++j)
        obase[(size_t)(gr + j) * OUTF + gc] = acc[ar][cc][j];
    }
  }
#undef STAGE_A
#undef STAGE_B
#undef RD_A
#undef RD_B
#undef BAR
#undef SB
#undef ISSUE_Q1
}

// ---------------------------------------------------------------------------
// Last-resort fallback (tiny ws): fused conversion GEMM.
// ---------------------------------------------------------------------------
__global__ __launch_bounds__(256) void gemm_fused(
    const float* __restrict__ xre, const float* __restrict__ xim,
    const float* __restrict__ wre, const float* __restrict__ wim,
    float* __restrict__ out)
{
  __shared__ alignas(16) bf16_t As[128 * 40];
  __shared__ alignas(16) bf16_t Bs[128 * 40];
  int tid = threadIdx.x;
  int bid = blockIdx.x;
  int swz = (bid & 7) * 128 + (bid >> 3);
  int bm = swz >> 5;
  int bn = swz & 31;
  int lane = tid & 63;
  int w    = tid >> 6;
  int wm   = (w >> 1) * 64;
  int wn   = (w & 1) * 64;
  int lr   = lane & 15;
  int lk   = (lane >> 4) * 8;
  f32x4 acc[4][4];
#pragma unroll
  for (int m = 0; m < 4; ++m)
#pragma unroll
    for (int n = 0; n < 4; ++n)
      acc[m][n] = (f32x4){0.f, 0.f, 0.f, 0.f};
  int srow = tid >> 3;
  int scol = (tid & 7) * 4;
  bool nIm  = (bn * 128) >= OUTF;
  int nbase = nIm ? (bn * 128 - OUTF) : (bn * 128);
  for (int kt = 0; kt < (2 * INF) / 32; ++kt) {
    int k0 = kt * 32;
    bool kHi = (k0 >= INF);
    int kk = kHi ? (k0 - INF) : k0;
    const float* Asrc = (kHi ? xim : xre) + (size_t)(bm * 128) * INF + kk;
    const float* Bsrc;
    float s = 1.0f;
    if (!nIm) { if (!kHi) { Bsrc = wre; } else { Bsrc = wim; s = -1.0f; } }
    else      { Bsrc = kHi ? wre : wim; }
    Bsrc += (size_t)nbase * INF + kk;
    float4 av[4], bv[4];
#pragma unroll
    for (int i = 0; i < 4; ++i) {
      av[i] = *reinterpret_cast<const float4*>(Asrc + (size_t)(srow + i * 32) * INF + scol);
      bv[i] = *reinterpret_cast<const float4*>(Bsrc + (size_t)(srow + i * 32) * INF + scol);
    }
    __syncthreads();
#pragma unroll
    for (int i = 0; i < 4; ++i) {
      bf16x4 a4, b4;
      a4[0] = (bf16_t)av[i].x; a4[1] = (bf16_t)av[i].y;
      a4[2] = (bf16_t)av[i].z; a4[3] = (bf16_t)av[i].w;
      b4[0] = (bf16_t)(bv[i].x * s); b4[1] = (bf16_t)(bv[i].y * s);
      b4[2] = (bf16_t)(bv[i].z * s); b4[3] = (bf16_t)(bv[i].w * s);
      *reinterpret_cast<bf16x4*>(&As[(srow + i * 32) * 40 + scol]) = a4;
      *reinterpret_cast<bf16x4*>(&Bs[(srow + i * 32) * 40 + scol]) = b4;
    }
    __syncthreads();
    bf16x8 a[4], b[4];
#pragma unroll
    for (int m = 0; m < 4; ++m)
      a[m] = *reinterpret_cast<const bf16x8*>(&As[(wm + m * 16 + lr) * 40 + lk]);
#pragma unroll
    for (int n = 0; n < 4; ++n)
      b[n] = *reinterpret_cast<const bf16x8*>(&Bs[(wn + n * 16 + lr) * 40 + lk]);
#pragma unroll
    for (int m = 0; m < 4; ++m)
#pragma unroll
      for (int n = 0; n < 4; ++n)
        acc[m][n] = __builtin_amdgcn_mfma_f32_16x16x32_bf16(a[m], b[n], acc[m][n], 0, 0, 0);
  }
  __syncthreads();
  const size_t imOff = (size_t)M_DIM * OUTF;
  int fq = (lane >> 4) * 4;
#pragma unroll
  for (int m = 0; m < 4; ++m) {
    int gr = bm * 128 + wm + m * 16 + fq;
#pragma unroll
    for (int n = 0; n < 4; ++n) {
      int gc = bn * 128 + wn + n * 16 + lr;
      float* dst = (gc < OUTF) ? (out + (size_t)gr * OUTF + gc)
                               : (out + imOff + (size_t)gr * OUTF + (gc - OUTF));
#pragma unroll
      for (int j = 0; j < 4; ++j)
        dst[(size_t)j * OUTF] = acc[m][n][j];
    }
  }
}

// ---------------------------------------------------------------------------
extern "C" void kernel_launch(void* const* d_in, const int* in_sizes, int n_in,
                              void* d_out, int out_size, void* d_ws, size_t ws_size,
                              hipStream_t stream) {
  const float* xre = (const float*)d_in[0];
  const float* xim = (const float*)d_in[1];
  const float* wre = (const float*)d_in[2];
  const float* wim = (const float*)d_in[3];
  float* out = (float*)d_out;

  const size_t need3m = (size_t)37748736 * sizeof(bf16_t);  // 72 MiB
  const size_t need2  = (size_t)2 * 4096 * 4096 * sizeof(bf16_t);  // 64 MiB
  if (ws_size >= need3m) {
    bf16_t* wsb = (bf16_t*)d_ws;
    hipLaunchKernelGGL(pack_3m, dim3(18432), dim3(256), 0, stream,
                       xre, xim, wre, wim, wsb);
    hipLaunchKernelGGL(gemm3m, dim3(256), dim3(512), 0, stream, wsb, out);
  } else if (ws_size >= need2) {
    bf16_t* Abf = (bf16_t*)d_ws;
    bf16_t* Bbf = Abf + (size_t)4096 * 4096;
    hipLaunchKernelGGL(pack_ab, dim3(16384), dim3(256), 0, stream,
                       xre, xim, wre, wim, Abf, Bbf);
    hipLaunchKernelGGL(gemm256, dim3(256), dim3(512), 0, stream,
                       Abf, Bbf, out);
  } else {
    hipLaunchKernelGGL(gemm_fused, dim3(1024), dim3(256), 0, stream,
                       xre, xim, wre, wim, out);
  }
}

// Round 15
// 142.047 us; speedup vs baseline: 1.1548x; 1.1548x over previous
//
#include <hip/hip_runtime.h>

typedef __bf16 bf16_t;
typedef __bf16 bf16x8 __attribute__((ext_vector_type(8)));
typedef __bf16 bf16x4 __attribute__((ext_vector_type(4)));
typedef float f32x4 __attribute__((ext_vector_type(4)));

#define M_DIM 4096
#define N_DIM 4096   // 2 * OUT_FEATURES
#define K_DIM 4096   // 2 * IN_FEATURES
#define OUTF 2048
#define INF 2048
#define LDK 4096
#define NT 64        // K-tiles of 64

// ---------------------------------------------------------------------------
// Pack kernel: build bf16 A = [x_re | x_im]  (4096 x 4096)
//              and  bf16 B = [[w_re, -w_im]; [w_im, w_re]] (4096 x 4096)
// ~24 us, at BW roofline (~200 MB moved).
// ---------------------------------------------------------------------------
__global__ __launch_bounds__(256) void pack_ab(
    const float* __restrict__ xre, const float* __restrict__ xim,
    const float* __restrict__ wre, const float* __restrict__ wim,
    bf16_t* __restrict__ Abf, bf16_t* __restrict__ Bbf)
{
  size_t gid = (size_t)blockIdx.x * 256 + threadIdx.x;
  size_t e8  = gid * 8;
  const size_t MAT = (size_t)4096 * 4096;
  bool isB = e8 >= MAT;
  size_t e = isB ? (e8 - MAT) : e8;
  int row = (int)(e >> 12);
  int k   = (int)(e & 4095);

  const float* src;
  float s = 1.0f;
  if (!isB) {
    src = (k < INF) ? (xre + (size_t)row * INF + k)
                    : (xim + (size_t)row * INF + (k - INF));
  } else {
    if (row < OUTF) {
      if (k < INF) { src = wre + (size_t)row * INF + k; }
      else         { src = wim + (size_t)row * INF + (k - INF); s = -1.0f; }
    } else {
      int o = row - OUTF;
      src = (k < INF) ? (wim + (size_t)o * INF + k)
                      : (wre + (size_t)o * INF + (k - INF));
    }
  }
  const float4* p = reinterpret_cast<const float4*>(src);
  float4 f0 = p[0];
  float4 f1 = p[1];
  bf16x8 v;
  v[0] = (bf16_t)(f0.x * s); v[1] = (bf16_t)(f0.y * s);
  v[2] = (bf16_t)(f0.z * s); v[3] = (bf16_t)(f0.w * s);
  v[4] = (bf16_t)(f1.x * s); v[5] = (bf16_t)(f1.y * s);
  v[6] = (bf16_t)(f1.z * s); v[7] = (bf16_t)(f1.w * s);
  bf16_t* dst = (isB ? Bbf : Abf) + e;
  *reinterpret_cast<bf16x8*>(dst) = v;
}

// ---------------------------------------------------------------------------
__device__ __forceinline__ void gld_lds16(const void* g, void* l) {
  __builtin_amdgcn_global_load_lds(
      (const __attribute__((address_space(1))) void*)g,
      (__attribute__((address_space(3))) void*)l,
      16, 0, 0);
}

// ---------------------------------------------------------------------------
// 256x256 GEMM, cross-tile read pipeline (R8 — best measured: 117.4 us,
// 1176 TF, MfmaUtil 51%, bank conflicts 0).
//   8 waves = 512 thr (2M x 4N), per-wave 128x64 out, BK=64, 128 KiB dbuf.
//   Swizzle (R3-verified, conflicts==0):
//     phys_kbyte = logical_kbyte ^ ((row&3)<<4) ^ (((row>>2)&1)<<6)
//   Tile t+1's Q1 reads (a0,b0) issue at tile t's P4 after {vmcnt(2); BAR}
//   and after MFMA Q4 (b0 last use); b1/a1 issued one phase early with
//   counted lgkm. 2 barriers/tile.
//   Session verdict (R3-R14): nine structural variants all within +-4% of
//   this — the m198-structure plateau; further gains need hand-asm codegen.
// ---------------------------------------------------------------------------

template<int QM, int QN>
__device__ __forceinline__ void mfma_quad(f32x4 (&acc)[8][4],
                                          const bf16x8 (&aF)[4][2],
                                          const bf16x8 (&bF)[2][2]) {
  __builtin_amdgcn_s_setprio(1);
#pragma unroll
  for (int m = 0; m < 4; ++m)
#pragma unroll
    for (int n = 0; n < 2; ++n) {
      f32x4 v = acc[QM * 4 + m][QN * 2 + n];
      v = __builtin_amdgcn_mfma_f32_16x16x32_bf16(aF[m][0], bF[n][0], v, 0, 0, 0);
      v = __builtin_amdgcn_mfma_f32_16x16x32_bf16(aF[m][1], bF[n][1], v, 0, 0, 0);
      acc[QM * 4 + m][QN * 2 + n] = v;
    }
  __builtin_amdgcn_s_setprio(0);
}

__global__ __launch_bounds__(512, 2) void gemm256(
    const bf16_t* __restrict__ A, const bf16_t* __restrict__ B,
    float* __restrict__ out)
{
  // LDS: buf c at c*65536 B; within buf: A-half0|A-half1|B-half0|B-half1,
  // each half = 128 rows x 64 cols bf16 = 16384 B (row stride 128 B).
  __shared__ alignas(16) bf16_t lds[2 * 32768];
  char* Lb = (char*)lds;

  const int tid  = threadIdx.x;
  const int lane = tid & 63;
  const int wid  = tid >> 6;
  const int wm   = wid >> 2;   // 0..1  -> rows wm*128..+127  (A-half wm)
  const int wn   = wid & 3;    // 0..3  -> cols wn*64..+63
  const int lr   = lane & 15;
  const int kg   = (lane >> 4) * 16;                         // logical slot
  const int xm   = ((lr & 3) << 4) | (((lr >> 2) & 1) << 6); // row-XOR mask

  int bid = blockIdx.x;
  int swz = (bid & 7) * 32 + (bid >> 3);   // XCD-aware, 256 blocks % 8 == 0
  const int bm = swz >> 4;                  // 0..15
  const int bn = swz & 15;                  // 0..15

  // Staging source precompute: physical P = j*8192 + tid*16 within a half;
  // row = P>>7, p = P&127; logical kbyte = p ^ ((row&3)<<4) ^ ((row>>2&1)<<6)
  int rS[2], kS[2];
#pragma unroll
  for (int j = 0; j < 2; ++j) {
    int P   = j * 8192 + tid * 16;
    int row = P >> 7;
    int p   = P & 127;
    int L   = p ^ ((row & 3) << 4) ^ (((row >> 2) & 1) << 6);
    rS[j] = row;
    kS[j] = L >> 1;           // k element (0..63)
  }
  const bf16_t* As0 = A + (size_t)(bm * 256 + rS[0]) * LDK + kS[0];
  const bf16_t* As1 = A + (size_t)(bm * 256 + rS[1]) * LDK + kS[1];
  const bf16_t* Bs0 = B + (size_t)(bn * 256 + rS[0]) * LDK + kS[0];
  const bf16_t* Bs1 = B + (size_t)(bn * 256 + rS[1]) * LDK + kS[1];
  const int dst16 = tid * 16;

#define STAGE_A(t, h, c) do {                                                  \
    gld_lds16(As0 + (size_t)(h) * 128 * LDK + (t) * 64,                        \
              Lb + (c) * 65536 + (h) * 16384 + dst16);                         \
    gld_lds16(As1 + (size_t)(h) * 128 * LDK + (t) * 64,                        \
              Lb + (c) * 65536 + (h) * 16384 + 8192 + dst16);                  \
  } while (0)
#define STAGE_B(t, h, c) do {                                                  \
    gld_lds16(Bs0 + (size_t)(h) * 128 * LDK + (t) * 64,                        \
              Lb + (c) * 65536 + 32768 + (h) * 16384 + dst16);                 \
    gld_lds16(Bs1 + (size_t)(h) * 128 * LDK + (t) * 64,                        \
              Lb + (c) * 65536 + 32768 + (h) * 16384 + 8192 + dst16);          \
  } while (0)
// A frag: row-in-half = qm*64+m*16+lr (half = wm); swizzled kbyte
#define RD_A(c, qm, m, ks)                                                     \
  (*(const bf16x8*)(Lb + (c) * 65536 + wm * 16384 +                            \
                    ((qm) * 64 + (m) * 16 + lr) * 128 +                        \
                    ((((ks) * 64) | kg) ^ xm)))
// B frag: row = wn*64+qn*32+n*16+lr -> half wn>>1, row-in-half rest
#define RD_B(c, qn, n, ks)                                                     \
  (*(const bf16x8*)(Lb + (c) * 65536 + 32768 + (wn >> 1) * 16384 +             \
                    ((wn & 1) * 64 + (qn) * 32 + (n) * 16 + lr) * 128 +        \
                    ((((ks) * 64) | kg) ^ xm)))
#define BAR()   __builtin_amdgcn_s_barrier()
#define SB()    __builtin_amdgcn_sched_barrier(0)
#define ISSUE_Q1(c) do {                                                       \
    _Pragma("unroll")                                                          \
    for (int m_ = 0; m_ < 4; ++m_) {                                           \
      a0[m_][0] = RD_A(c, 0, m_, 0);                                           \
      a0[m_][1] = RD_A(c, 0, m_, 1);                                           \
    }                                                                          \
    _Pragma("unroll")                                                          \
    for (int n_ = 0; n_ < 2; ++n_) {                                           \
      b0[n_][0] = RD_B(c, 0, n_, 0);                                           \
      b0[n_][1] = RD_B(c, 0, n_, 1);                                           \
    }                                                                          \
  } while (0)

  f32x4 acc[8][4];
#pragma unroll
  for (int i = 0; i < 8; ++i)
#pragma unroll
    for (int j = 0; j < 4; ++j)
      acc[i][j] = (f32x4){0.f, 0.f, 0.f, 0.f};

  bf16x8 a0[4][2], b0[2][2];   // loop-carried: Q1 frags of the CURRENT tile

  // Prologue: tile0 fully into buf0 (8 loads); tile1's A0 into buf1 (2).
  // vmcnt(2): tile0 resident (t1-A0 in flight). Then issue Q1(t0).
  STAGE_A(0, 0, 0); STAGE_A(0, 1, 0);
  STAGE_B(0, 0, 0); STAGE_B(0, 1, 0);
  STAGE_A(1, 0, 1);
  asm volatile("s_waitcnt vmcnt(2)" ::: "memory");
  BAR();
  ISSUE_Q1(0);
  SB();

  for (int t = 0; t < NT; ++t) {
    const int c = t & 1;
    bf16x8 a1[4][2], b1[2][2];

    // ---- P1: stage t+1 A1; issue b1 (drains under Q1 MFMA).
    // lgkm(4): Q1's 12 done (issued last tile's P4, ~1 phase of cover).
    if (t + 1 < NT) STAGE_A(t + 1, 1, c ^ 1);
#pragma unroll
    for (int n = 0; n < 2; ++n) {
      b1[n][0] = RD_B(c, 1, n, 0);
      b1[n][1] = RD_B(c, 1, n, 1);
    }
    SB();
    asm volatile("s_waitcnt lgkmcnt(4)" ::: "memory");
    SB();
    mfma_quad<0, 0>(acc, a0, b0);

    // ---- P2: stage t+1 B0; issue a1 (drains under Q2). lgkm(8): b1 done.
    if (t + 1 < NT) STAGE_B(t + 1, 0, c ^ 1);
#pragma unroll
    for (int m = 0; m < 4; ++m) {
      a1[m][0] = RD_A(c, 1, m, 0);
      a1[m][1] = RD_A(c, 1, m, 1);
    }
    SB();
    asm volatile("s_waitcnt lgkmcnt(8)" ::: "memory");
    SB();
    mfma_quad<0, 1>(acc, a0, b1);

    // ---- P3: stage t+1 B1; lgkm(0): a1 done. BAR: all waves' buf-c reads
    // complete -> t+2 staging into c is safe (and bounds wave skew).
    if (t + 1 < NT) STAGE_B(t + 1, 1, c ^ 1);
    asm volatile("s_waitcnt lgkmcnt(0)" ::: "memory");
    SB();
    mfma_quad<1, 1>(acc, a1, b1);
    BAR();

    // ---- P4: stage t+2 A0 into buf c; vmcnt(2)+BAR: every wave's t+1
    // staging loads drained -> buf c^1 globally resident. MFMA Q4 (last use
    // of b0), THEN issue next tile's Q1 into a0/b0 (drains under Q4 exec).
    if (t + 2 < NT) STAGE_A(t + 2, 0, c);
    if (t + 2 < NT) {
      asm volatile("s_waitcnt vmcnt(2)" ::: "memory");
    } else if (t + 1 < NT) {
      asm volatile("s_waitcnt vmcnt(0)" ::: "memory");
    }
    BAR();
    mfma_quad<1, 0>(acc, a1, b0);
    if (t + 1 < NT) {
      SB();
      ISSUE_Q1(c ^ 1);
      SB();
    }
  }

  // Epilogue: C/D layout col=lane&15, row=(lane>>4)*4+j (verified m89/m91)
  const size_t imOff = (size_t)M_DIM * OUTF;
  const int fq = (lane >> 4) * 4;
  const bool isIm = (bn * 256) >= OUTF;          // bn>=8 -> imaginary half
  float* obase = out + (isIm ? imOff : 0);
  const int colBase = bn * 256 - (isIm ? OUTF : 0) + wn * 64;
#pragma unroll
  for (int ar = 0; ar < 8; ++ar) {
    int gr = bm * 256 + wm * 128 + ar * 16 + fq;
#pragma unroll
    for (int cc = 0; cc < 4; ++cc) {
      int gc = colBase + cc * 16 + lr;
#pragma unroll
      for (int j = 0; j < 4; ++j)
        obase[(size_t)(gr + j) * OUTF + gc] = acc[ar][cc][j];
    }
  }
#undef STAGE_A
#undef STAGE_B
#undef RD_A
#undef RD_B
#undef BAR
#undef SB
#undef ISSUE_Q1
}

// ---------------------------------------------------------------------------
// Fallback: fused fp32->bf16 conversion + GEMM (no workspace needed).
// ---------------------------------------------------------------------------
__global__ __launch_bounds__(256) void gemm_fused(
    const float* __restrict__ xre, const float* __restrict__ xim,
    const float* __restrict__ wre, const float* __restrict__ wim,
    float* __restrict__ out)
{
  __shared__ alignas(16) bf16_t As[128 * 40];
  __shared__ alignas(16) bf16_t Bs[128 * 40];

  int tid = threadIdx.x;
  int bid = blockIdx.x;
  int swz = (bid & 7) * 128 + (bid >> 3);
  int bm = swz >> 5;
  int bn = swz & 31;

  int lane = tid & 63;
  int w    = tid >> 6;
  int wm   = (w >> 1) * 64;
  int wn   = (w & 1) * 64;
  int lr   = lane & 15;
  int lk   = (lane >> 4) * 8;

  f32x4 acc[4][4];
#pragma unroll
  for (int m = 0; m < 4; ++m)
#pragma unroll
    for (int n = 0; n < 4; ++n)
      acc[m][n] = (f32x4){0.f, 0.f, 0.f, 0.f};

  int srow = tid >> 3;
  int scol = (tid & 7) * 4;

  bool nIm  = (bn * 128) >= OUTF;
  int nbase = nIm ? (bn * 128 - OUTF) : (bn * 128);

  for (int kt = 0; kt < K_DIM / 32; ++kt) {
    int k0 = kt * 32;
    bool kHi = (k0 >= INF);
    int kk = kHi ? (k0 - INF) : k0;

    const float* Asrc = (kHi ? xim : xre) + (size_t)(bm * 128) * INF + kk;
    const float* Bsrc;
    float s = 1.0f;
    if (!nIm) { if (!kHi) { Bsrc = wre; } else { Bsrc = wim; s = -1.0f; } }
    else      { Bsrc = kHi ? wre : wim; }
    Bsrc += (size_t)nbase * INF + kk;

    float4 av[4], bv[4];
#pragma unroll
    for (int i = 0; i < 4; ++i) {
      av[i] = *reinterpret_cast<const float4*>(Asrc + (size_t)(srow + i * 32) * INF + scol);
      bv[i] = *reinterpret_cast<const float4*>(Bsrc + (size_t)(srow + i * 32) * INF + scol);
    }
    __syncthreads();
#pragma unroll
    for (int i = 0; i < 4; ++i) {
      bf16x4 a4, b4;
      a4[0] = (bf16_t)av[i].x; a4[1] = (bf16_t)av[i].y;
      a4[2] = (bf16_t)av[i].z; a4[3] = (bf16_t)av[i].w;
      b4[0] = (bf16_t)(bv[i].x * s); b4[1] = (bf16_t)(bv[i].y * s);
      b4[2] = (bf16_t)(bv[i].z * s); b4[3] = (bf16_t)(bv[i].w * s);
      *reinterpret_cast<bf16x4*>(&As[(srow + i * 32) * 40 + scol]) = a4;
      *reinterpret_cast<bf16x4*>(&Bs[(srow + i * 32) * 40 + scol]) = b4;
    }
    __syncthreads();

    bf16x8 a[4], b[4];
#pragma unroll
    for (int m = 0; m < 4; ++m)
      a[m] = *reinterpret_cast<const bf16x8*>(&As[(wm + m * 16 + lr) * 40 + lk]);
#pragma unroll
    for (int n = 0; n < 4; ++n)
      b[n] = *reinterpret_cast<const bf16x8*>(&Bs[(wn + n * 16 + lr) * 40 + lk]);
#pragma unroll
    for (int m = 0; m < 4; ++m)
#pragma unroll
      for (int n = 0; n < 4; ++n)
        acc[m][n] = __builtin_amdgcn_mfma_f32_16x16x32_bf16(a[m], b[n], acc[m][n], 0, 0, 0);
  }
  __syncthreads();

  const size_t imOff = (size_t)M_DIM * OUTF;
  int fq = (lane >> 4) * 4;
#pragma unroll
  for (int m = 0; m < 4; ++m) {
    int gr = bm * 128 + wm + m * 16 + fq;
#pragma unroll
    for (int n = 0; n < 4; ++n) {
      int gc = bn * 128 + wn + n * 16 + lr;
      float* dst = (gc < OUTF) ? (out + (size_t)gr * OUTF + gc)
                               : (out + imOff + (size_t)gr * OUTF + (gc - OUTF));
#pragma unroll
      for (int j = 0; j < 4; ++j)
        dst[(size_t)j * OUTF] = acc[m][n][j];
    }
  }
}

// ---------------------------------------------------------------------------
extern "C" void kernel_launch(void* const* d_in, const int* in_sizes, int n_in,
                              void* d_out, int out_size, void* d_ws, size_t ws_size,
                              hipStream_t stream) {
  const float* xre = (const float*)d_in[0];
  const float* xim = (const float*)d_in[1];
  const float* wre = (const float*)d_in[2];
  const float* wim = (const float*)d_in[3];
  float* out = (float*)d_out;

  const size_t need = (size_t)2 * 4096 * 4096 * sizeof(bf16_t);  // 64 MiB
  if (ws_size >= need) {
    bf16_t* Abf = (bf16_t*)d_ws;
    bf16_t* Bbf = Abf + (size_t)4096 * 4096;
    hipLaunchKernelGGL(pack_ab, dim3(16384), dim3(256), 0, stream,
                       xre, xim, wre, wim, Abf, Bbf);
    hipLaunchKernelGGL(gemm256, dim3(256), dim3(512), 0, stream,
                       Abf, Bbf, out);
  } else {
    hipLaunchKernelGGL(gemm_fused, dim3(1024), dim3(256), 0, stream,
                       xre, xim, wre, wim, out);
  }
}